// Round 1
// baseline (1301.775 us; speedup 1.0000x reference)
//
#include <hip/hip_runtime.h>

// out[b,j] = sum_i x[b,i,i] * P[i,j]   (P rows are one-hot)
// dim = 8855, B = 4, NVAL = 15 -> out has 60 floats.

#define NVAL 15

__global__ void zero_out_kernel(float* out, int n) {
    int t = blockIdx.x * blockDim.x + threadIdx.x;
    if (t < n) out[t] = 0.0f;
}

__global__ __launch_bounds__(256) void diag_proj_kernel(
        const float* __restrict__ x,   // [B, dim, dim]
        const float* __restrict__ P,   // [dim, NVAL]
        float* __restrict__ out,       // [B, NVAL]
        int dim) {
    __shared__ float bins[NVAL];
    const int t = threadIdx.x;
    if (t < NVAL) bins[t] = 0.0f;
    __syncthreads();

    const int i = blockIdx.x * blockDim.x + t;
    const int b = blockIdx.y;

    if (i < dim) {
        // diagonal element: stride dim+1 within batch b
        const size_t base = (size_t)b * (size_t)dim * (size_t)dim;
        const float d = x[base + (size_t)i * (size_t)(dim + 1)];

        // find the single nonzero column of P row i
        int j = 0;
        const float* __restrict__ prow = P + (size_t)i * NVAL;
#pragma unroll
        for (int jj = 0; jj < NVAL; ++jj) {
            if (prow[jj] != 0.0f) j = jj;
        }
        atomicAdd(&bins[j], d);
    }
    __syncthreads();

    if (t < NVAL) {
        const float v = bins[t];
        if (v != 0.0f) atomicAdd(&out[b * NVAL + t], v);
    }
}

extern "C" void kernel_launch(void* const* d_in, const int* in_sizes, int n_in,
                              void* d_out, int out_size, void* d_ws, size_t ws_size,
                              hipStream_t stream) {
    const float* x = (const float*)d_in[0];
    const float* P = (const float*)d_in[1];
    float* out = (float*)d_out;

    const int dim = in_sizes[1] / NVAL;           // 8855
    const int B   = (int)(in_sizes[0] / ((long long)dim * dim)); // 4

    // d_out is poisoned 0xAA before every timed launch -> zero it first.
    zero_out_kernel<<<(out_size + 63) / 64, 64, 0, stream>>>(out, out_size);

    dim3 grid((dim + 255) / 256, B);
    diag_proj_kernel<<<grid, 256, 0, stream>>>(x, P, out, dim);
}